// Round 1
// baseline (401.513 us; speedup 1.0000x reference)
//
#include <hip/hip_runtime.h>
#include <math.h>

#define N_NODES 100000
#define N_EDGES 500000
#define E_HID   64
#define R_HID   32
#define N_RELS  500
#define EPSF    1e-16f
#define D_OUT   224   // 64 (x) + 160 (e_features)

// --- Kernel 1: per-node score scalars  s_i[n]=x[n]·w[0:64], s_j[n]=x[n]·w[96:160]
// one wave (64 lanes) per node; lane k handles element k -> fully coalesced x read
__global__ void node_scores_kernel(const float* __restrict__ x,
                                   const float* __restrict__ w,
                                   float* __restrict__ s_i,
                                   float* __restrict__ s_j) {
    int node = (blockIdx.x * blockDim.x + threadIdx.x) >> 6;
    int lane = threadIdx.x & 63;
    if (node >= N_NODES) return;
    float v = x[node * E_HID + lane];
    float a = v * w[lane];          // w[0:64]   (x[ei] part)
    float b = v * w[96 + lane];     // w[96:160] (x[ej] part)
    #pragma unroll
    for (int off = 32; off > 0; off >>= 1) {
        a += __shfl_down(a, off);
        b += __shfl_down(b, off);
    }
    if (lane == 0) { s_i[node] = a; s_j[node] = b; }
}

// --- Kernel 2: per-relation score scalars  s_r[r] = rel_emb[r]·w[64:96]
// 32 lanes per relation
__global__ void rel_scores_kernel(const float* __restrict__ rel_emb,
                                  const float* __restrict__ w,
                                  float* __restrict__ s_r) {
    int r    = (blockIdx.x * blockDim.x + threadIdx.x) >> 5;
    int lane = threadIdx.x & 31;
    if (r >= N_RELS) return;
    float a = rel_emb[r * R_HID + lane] * w[64 + lane];
    #pragma unroll
    for (int off = 16; off > 0; off >>= 1) a += __shfl_down(a, off, 32);
    if (lane == 0) s_r[r] = a;
}

// --- Kernel 3: per-edge exp(att) and segment sum (no max-subtract: |att| <~ 4)
__global__ void edge_exp_kernel(const int* __restrict__ ei,
                                const int* __restrict__ ej,
                                const int* __restrict__ rel,
                                const float* __restrict__ s_i,
                                const float* __restrict__ s_j,
                                const float* __restrict__ s_r,
                                float* __restrict__ s_edge,
                                float* __restrict__ seg_sum) {
    int e = blockIdx.x * blockDim.x + threadIdx.x;
    if (e >= N_EDGES) return;
    int d = ei[e];
    float att = s_i[d] + s_r[rel[e]] + s_j[ej[e]];
    float s = expf(att);
    s_edge[e] = s;
    atomicAdd(&seg_sum[d], s);
}

// --- Kernel 4: weighted scatter of the non-trivial 96 feature columns
// flat mapping: thread -> (edge e, col c in [0,96));  c<32: rel part, else x[ej] part.
// Targets d_out columns [128,224) directly (d_out pre-zeroed).
__global__ void edge_scatter_kernel(const int* __restrict__ ei,
                                    const int* __restrict__ ej,
                                    const int* __restrict__ rel,
                                    const float* __restrict__ x,
                                    const float* __restrict__ rel_emb,
                                    const float* __restrict__ s_edge,
                                    const float* __restrict__ seg_sum,
                                    float* __restrict__ out) {
    int idx = blockIdx.x * blockDim.x + threadIdx.x;
    if (idx >= N_EDGES * 96) return;           // 48e6 < 2^31
    int e = idx / 96;
    int c = idx - e * 96;
    int d = ei[e];
    float w = s_edge[e] / (seg_sum[d] + EPSF);
    float v;
    int col;
    if (c < R_HID) {
        v = w * rel_emb[rel[e] * R_HID + c];
        col = 128 + c;                          // e_features cols [64,96) -> out [128,160)
    } else {
        int c2 = c - R_HID;
        v = w * x[ej[e] * E_HID + c2];
        col = 160 + c2;                         // e_features cols [96,160) -> out [160,224)
    }
    atomicAdd(&out[d * D_OUT + col], v);
}

// --- Kernel 5: finalize. cols 0:64 = x;  cols 64:128 = relu(alpha*x);
//               cols 128:224 = relu(accumulated) in place.
__global__ void finalize_kernel(const float* __restrict__ x,
                                const float* __restrict__ seg_sum,
                                float* __restrict__ out) {
    int idx = blockIdx.x * blockDim.x + threadIdx.x;
    if (idx >= N_NODES * D_OUT) return;        // 22.4e6
    int n = idx / D_OUT;
    int c = idx - n * D_OUT;
    if (c < 64) {
        out[idx] = x[n * E_HID + c];
    } else if (c < 128) {
        float S = seg_sum[n];
        float alpha = S / (S + EPSF);           // = sum of softmax weights (0 if no edges)
        out[idx] = fmaxf(alpha * x[n * E_HID + (c - 64)], 0.0f);
    } else {
        out[idx] = fmaxf(out[idx], 0.0f);
    }
}

extern "C" void kernel_launch(void* const* d_in, const int* in_sizes, int n_in,
                              void* d_out, int out_size, void* d_ws, size_t ws_size,
                              hipStream_t stream) {
    const float* x        = (const float*)d_in[0];               // [N, 64]
    const int*   edge_all = (const int*)  d_in[1];               // [2, E] flat
    const int*   rel      = (const int*)  d_in[2];               // [E]
    const float* rel_emb  = (const float*)d_in[3];               // [500, 32]
    const float* ww       = (const float*)d_in[4];               // [160]
    float*       out      = (float*)d_out;                       // [N, 224]

    const int* ei = edge_all;            // destinations (group index)
    const int* ej = edge_all + N_EDGES;  // sources

    // workspace layout (floats): s_i[N] | s_j[N] | seg_sum[N] | s_r[512] | s_edge[E]
    float* s_i     = (float*)d_ws;
    float* s_j     = s_i + N_NODES;
    float* seg_sum = s_j + N_NODES;
    float* s_r     = seg_sum + N_NODES;
    float* s_edge  = s_r + 512;

    // zero the accumulators (d_out / d_ws are poisoned with 0xAA before each call)
    hipMemsetAsync(d_out, 0, (size_t)N_NODES * D_OUT * sizeof(float), stream);
    hipMemsetAsync(seg_sum, 0, (size_t)N_NODES * sizeof(float), stream);

    {   // node scores: one 64-lane wave per node, 4 nodes per 256-block
        int blocks = (N_NODES + 3) / 4;
        node_scores_kernel<<<blocks, 256, 0, stream>>>(x, ww, s_i, s_j);
    }
    {   // rel scores: 8 rels per 256-block
        int blocks = (N_RELS + 7) / 8;
        rel_scores_kernel<<<blocks, 256, 0, stream>>>(rel_emb, ww, s_r);
    }
    {   // per-edge exp + segment sums
        int blocks = (N_EDGES + 255) / 256;
        edge_exp_kernel<<<blocks, 256, 0, stream>>>(ei, ej, rel, s_i, s_j, s_r,
                                                    s_edge, seg_sum);
    }
    {   // weighted scatter (the heavy pass)
        long long work = (long long)N_EDGES * 96;
        int blocks = (int)((work + 255) / 256);
        edge_scatter_kernel<<<blocks, 256, 0, stream>>>(ei, ej, rel, x, rel_emb,
                                                        s_edge, seg_sum, out);
    }
    {   // finalize
        long long work = (long long)N_NODES * D_OUT;
        int blocks = (int)((work + 255) / 256);
        finalize_kernel<<<blocks, 256, 0, stream>>>(x, seg_sum, out);
    }
}

// Round 2
// 294.572 us; speedup vs baseline: 1.3630x; 1.3630x over previous
//
#include <hip/hip_runtime.h>
#include <math.h>

#define N_NODES 100000
#define N_EDGES 500000
#define E_HID   64
#define R_HID   32
#define N_RELS  500
#define EPSF    1e-16f
#define D_OUT   224   // 64 (x) + 160 (e_features)

#define SCAN_B  512   // elements per scan block
#define SCAN_NB ((N_NODES + SCAN_B - 1) / SCAN_B)   // 196

// --- Kernel 1: per-node score scalars  s_i[n]=x[n]·w[0:64], s_j[n]=x[n]·w[96:160]
__global__ void node_scores_kernel(const float* __restrict__ x,
                                   const float* __restrict__ w,
                                   float* __restrict__ s_i,
                                   float* __restrict__ s_j) {
    int node = (blockIdx.x * blockDim.x + threadIdx.x) >> 6;
    int lane = threadIdx.x & 63;
    if (node >= N_NODES) return;
    float v = x[node * E_HID + lane];
    float a = v * w[lane];
    float b = v * w[96 + lane];
    #pragma unroll
    for (int off = 32; off > 0; off >>= 1) {
        a += __shfl_down(a, off);
        b += __shfl_down(b, off);
    }
    if (lane == 0) { s_i[node] = a; s_j[node] = b; }
}

// --- Kernel 2: per-relation score scalars  s_r[r] = rel_emb[r]·w[64:96]
__global__ void rel_scores_kernel(const float* __restrict__ rel_emb,
                                  const float* __restrict__ w,
                                  float* __restrict__ s_r) {
    int r    = (blockIdx.x * blockDim.x + threadIdx.x) >> 5;
    int lane = threadIdx.x & 31;
    if (r >= N_RELS) return;
    float a = rel_emb[r * R_HID + lane] * w[64 + lane];
    #pragma unroll
    for (int off = 16; off > 0; off >>= 1) a += __shfl_down(a, off, 32);
    if (lane == 0) s_r[r] = a;
}

// --- Kernel 3: histogram of destinations
__global__ void hist_kernel(const int* __restrict__ ei, int* __restrict__ count) {
    int e = blockIdx.x * blockDim.x + threadIdx.x;
    if (e >= N_EDGES) return;
    atomicAdd(&count[ei[e]], 1);
}

// --- Kernel 4a: per-block exclusive scan (Hillis-Steele in LDS)
__global__ void scan1_kernel(const int* __restrict__ count,
                             int* __restrict__ starts,
                             int* __restrict__ bsums) {
    __shared__ int tmp[SCAN_B];
    int tid = threadIdx.x;
    int gid = blockIdx.x * SCAN_B + tid;
    int v = (gid < N_NODES) ? count[gid] : 0;
    tmp[tid] = v;
    __syncthreads();
    #pragma unroll
    for (int off = 1; off < SCAN_B; off <<= 1) {
        int t = (tid >= off) ? tmp[tid - off] : 0;
        __syncthreads();
        tmp[tid] += t;
        __syncthreads();
    }
    if (gid < N_NODES) starts[gid] = tmp[tid] - v;   // exclusive
    if (tid == SCAN_B - 1) bsums[blockIdx.x] = tmp[tid];
}

// --- Kernel 4b: scan the block sums (single block; SCAN_NB=196 <= 256)
__global__ void scan2_kernel(int* __restrict__ bsums) {
    __shared__ int tmp[256];
    int tid = threadIdx.x;
    int v = (tid < SCAN_NB) ? bsums[tid] : 0;
    tmp[tid] = v;
    __syncthreads();
    #pragma unroll
    for (int off = 1; off < 256; off <<= 1) {
        int t = (tid >= off) ? tmp[tid - off] : 0;
        __syncthreads();
        tmp[tid] += t;
        __syncthreads();
    }
    if (tid < SCAN_NB) bsums[tid] = tmp[tid] - v;    // exclusive
}

// --- Kernel 4c: add block offsets
__global__ void scan3_kernel(int* __restrict__ starts, const int* __restrict__ bsums) {
    int gid = blockIdx.x * SCAN_B + threadIdx.x;
    if (gid < N_NODES) starts[gid] += bsums[blockIdx.x];
}

// --- Kernel 5: place edge ids into CSR order
__global__ void place_kernel(const int* __restrict__ ei,
                             const int* __restrict__ starts,
                             int* __restrict__ cursor,
                             int* __restrict__ sorted) {
    int e = blockIdx.x * blockDim.x + threadIdx.x;
    if (e >= N_EDGES) return;
    int d = ei[e];
    int pos = starts[d] + atomicAdd(&cursor[d], 1);
    sorted[pos] = e;
}

// --- Kernel 6: fused per-node aggregate. One 64-lane wave per node.
// x_e = (sum_e se*feat_e) / (sum_e se + eps)   (normalization is linear)
__global__ void node_aggregate_kernel(const int* __restrict__ ej,
                                      const int* __restrict__ rel,
                                      const int* __restrict__ sorted,
                                      const int* __restrict__ starts,
                                      const int* __restrict__ count,
                                      const float* __restrict__ x,
                                      const float* __restrict__ rel_emb,
                                      const float* __restrict__ s_i,
                                      const float* __restrict__ s_j,
                                      const float* __restrict__ s_r,
                                      float* __restrict__ out) {
    int node = (blockIdx.x * blockDim.x + threadIdx.x) >> 6;
    int lane = threadIdx.x & 63;
    if (node >= N_NODES) return;
    int beg = starts[node];
    int cnt = count[node];
    float si = s_i[node];
    float S = 0.0f, accx = 0.0f, accr = 0.0f;
    for (int k = 0; k < cnt; k++) {
        int e   = sorted[beg + k];      // same addr across wave -> broadcast
        int src = ej[e];
        int r   = rel[e];
        float se = expf(si + s_r[r] + s_j[src]);   // |att| small: no max needed
        S    += se;
        accx += se * x[src * E_HID + lane];        // coalesced 256B row
        if (lane < R_HID) accr += se * rel_emb[r * R_HID + lane];
    }
    float w  = 1.0f / (S + EPSF);
    float xv = x[node * E_HID + lane];
    float* o = out + (size_t)node * D_OUT;
    o[lane]       = xv;                             // cols 0:64 = x
    o[64 + lane]  = fmaxf(S * w * xv, 0.0f);        // cols 64:128 = relu(alpha*x)
    if (lane < R_HID)
        o[128 + lane] = fmaxf(accr * w, 0.0f);      // cols 128:160 = rel part
    o[160 + lane] = fmaxf(accx * w, 0.0f);          // cols 160:224 = x[ej] part
}

extern "C" void kernel_launch(void* const* d_in, const int* in_sizes, int n_in,
                              void* d_out, int out_size, void* d_ws, size_t ws_size,
                              hipStream_t stream) {
    const float* x        = (const float*)d_in[0];               // [N, 64]
    const int*   edge_all = (const int*)  d_in[1];               // [2, E] flat
    const int*   rel      = (const int*)  d_in[2];               // [E]
    const float* rel_emb  = (const float*)d_in[3];               // [500, 32]
    const float* ww       = (const float*)d_in[4];               // [160]
    float*       out      = (float*)d_out;                       // [N, 224]

    const int* ei = edge_all;            // destinations (group index)
    const int* ej = edge_all + N_EDGES;  // sources

    // workspace layout:
    // floats: s_i[N] | s_j[N] | s_r[512]
    // ints:   count[N] | starts[N] | cursor[N] | bsums[512] | sorted[E]
    float* s_i    = (float*)d_ws;
    float* s_j    = s_i + N_NODES;
    float* s_r    = s_j + N_NODES;
    int*   count  = (int*)(s_r + 512);
    int*   starts = count + N_NODES;
    int*   cursor = starts + N_NODES;
    int*   bsums  = cursor + N_NODES;
    int*   sorted = bsums + 512;

    hipMemsetAsync(count,  0, (size_t)N_NODES * sizeof(int), stream);
    hipMemsetAsync(cursor, 0, (size_t)N_NODES * sizeof(int), stream);

    node_scores_kernel<<<(N_NODES + 3) / 4, 256, 0, stream>>>(x, ww, s_i, s_j);
    rel_scores_kernel<<<(N_RELS + 7) / 8, 256, 0, stream>>>(rel_emb, ww, s_r);
    hist_kernel<<<(N_EDGES + 255) / 256, 256, 0, stream>>>(ei, count);
    scan1_kernel<<<SCAN_NB, SCAN_B, 0, stream>>>(count, starts, bsums);
    scan2_kernel<<<1, 256, 0, stream>>>(bsums);
    scan3_kernel<<<SCAN_NB, SCAN_B, 0, stream>>>(starts, bsums);
    place_kernel<<<(N_EDGES + 255) / 256, 256, 0, stream>>>(ei, starts, cursor, sorted);
    node_aggregate_kernel<<<(N_NODES + 3) / 4, 256, 0, stream>>>(
        ej, rel, sorted, starts, count, x, rel_emb, s_i, s_j, s_r, out);
}

// Round 3
// 217.761 us; speedup vs baseline: 1.8438x; 1.3527x over previous
//
#include <hip/hip_runtime.h>
#include <math.h>

#define N_NODES 100000
#define N_EDGES 500000
#define E_HID   64
#define R_HID   32
#define N_RELS  500
#define EPSF    1e-16f
#define D_OUT   224   // 64 (x) + 160 (e_features)

#define SCAN_B  512
#define SCAN_NB ((N_NODES + SCAN_B - 1) / SCAN_B)   // 196

// fused pre-kernel block ranges
#define NS_BLOCKS ((N_NODES + 3) / 4)               // 25000 (4 nodes / 256-thread block)
#define RS_BLOCKS ((N_RELS + 7) / 8)                // 63    (8 rels / block)
#define HIST_BLOCKS ((N_EDGES + 255) / 256)         // 1954
#define PRE_GRID (NS_BLOCKS + RS_BLOCKS + HIST_BLOCKS)

// --- Kernel 1 (fused): node score scalars + rel score scalars + dest histogram.
// Three independent phases mapped to disjoint block ranges -> one launch.
__global__ void fused_pre_kernel(const float* __restrict__ x,
                                 const float* __restrict__ rel_emb,
                                 const float* __restrict__ w,
                                 const int* __restrict__ ei,
                                 float* __restrict__ s_i,
                                 float* __restrict__ s_j,
                                 float* __restrict__ s_r,
                                 int* __restrict__ count) {
    int b = blockIdx.x;
    if (b < NS_BLOCKS) {
        // s_i[n] = x[n]·w[0:64], s_j[n] = x[n]·w[96:160]; one 64-lane wave/node
        int node = (b * 256 + threadIdx.x) >> 6;
        int lane = threadIdx.x & 63;
        if (node >= N_NODES) return;
        float v = x[node * E_HID + lane];
        float a  = v * w[lane];
        float bb = v * w[96 + lane];
        #pragma unroll
        for (int off = 32; off > 0; off >>= 1) {
            a  += __shfl_down(a, off);
            bb += __shfl_down(bb, off);
        }
        if (lane == 0) { s_i[node] = a; s_j[node] = bb; }
    } else if (b < NS_BLOCKS + RS_BLOCKS) {
        // s_r[r] = rel_emb[r]·w[64:96]; 32 lanes per relation
        int r    = ((b - NS_BLOCKS) * 256 + threadIdx.x) >> 5;
        int lane = threadIdx.x & 31;
        if (r >= N_RELS) return;
        float a = rel_emb[r * R_HID + lane] * w[64 + lane];
        #pragma unroll
        for (int off = 16; off > 0; off >>= 1) a += __shfl_down(a, off, 32);
        if (lane == 0) s_r[r] = a;
    } else {
        // histogram of destinations
        int e = (b - NS_BLOCKS - RS_BLOCKS) * 256 + threadIdx.x;
        if (e < N_EDGES) atomicAdd(&count[ei[e]], 1);
    }
}

// --- Kernel 2a: per-block exclusive scan (Hillis-Steele in LDS)
__global__ void scan1_kernel(const int* __restrict__ count,
                             int* __restrict__ starts,
                             int* __restrict__ bsums) {
    __shared__ int tmp[SCAN_B];
    int tid = threadIdx.x;
    int gid = blockIdx.x * SCAN_B + tid;
    int v = (gid < N_NODES) ? count[gid] : 0;
    tmp[tid] = v;
    __syncthreads();
    #pragma unroll
    for (int off = 1; off < SCAN_B; off <<= 1) {
        int t = (tid >= off) ? tmp[tid - off] : 0;
        __syncthreads();
        tmp[tid] += t;
        __syncthreads();
    }
    if (gid < N_NODES) starts[gid] = tmp[tid] - v;   // exclusive
    if (tid == SCAN_B - 1) bsums[blockIdx.x] = tmp[tid];
}

// --- Kernel 2b: scan the block sums (single block; SCAN_NB=196 <= 256)
__global__ void scan2_kernel(int* __restrict__ bsums) {
    __shared__ int tmp[256];
    int tid = threadIdx.x;
    int v = (tid < SCAN_NB) ? bsums[tid] : 0;
    tmp[tid] = v;
    __syncthreads();
    #pragma unroll
    for (int off = 1; off < 256; off <<= 1) {
        int t = (tid >= off) ? tmp[tid - off] : 0;
        __syncthreads();
        tmp[tid] += t;
        __syncthreads();
    }
    if (tid < SCAN_NB) bsums[tid] = tmp[tid] - v;    // exclusive
}

// --- Kernel 2c: add block offsets
__global__ void scan3_kernel(int* __restrict__ starts, const int* __restrict__ bsums) {
    int gid = blockIdx.x * SCAN_B + threadIdx.x;
    if (gid < N_NODES) starts[gid] += bsums[blockIdx.x];
}

// --- Kernel 3: place edge PAYLOAD into CSR order: {src, rel, expf(att)}.
// Post-increments starts[] itself (afterwards starts[d] == segment end).
__global__ void place_kernel(const int* __restrict__ ei,
                             const int* __restrict__ ej,
                             const int* __restrict__ rel,
                             const float* __restrict__ s_i,
                             const float* __restrict__ s_j,
                             const float* __restrict__ s_r,
                             int* __restrict__ starts,
                             int4* __restrict__ pack) {
    int e = blockIdx.x * blockDim.x + threadIdx.x;
    if (e >= N_EDGES) return;
    int d   = ei[e];
    int src = ej[e];
    int r   = rel[e];
    float se = expf(s_i[d] + s_r[r] + s_j[src]);   // |att| ~ 0.6 std: no max needed
    int pos = atomicAdd(&starts[d], 1);
    pack[pos] = make_int4(src, r, __float_as_int(se), 0);
}

// --- Kernel 4: fused per-node aggregate. One 64-lane wave per node.
// Per edge: one broadcast int4 load -> independent x-row gather. Unrolled x4
// so 4 gathers are in flight per wave.
__global__ void node_aggregate_kernel(const int4* __restrict__ pack,
                                      const int* __restrict__ starts_end,
                                      const int* __restrict__ count,
                                      const float* __restrict__ x,
                                      const float* __restrict__ rel_emb,
                                      float* __restrict__ out) {
    int node = (blockIdx.x * blockDim.x + threadIdx.x) >> 6;
    int lane = threadIdx.x & 63;
    if (node >= N_NODES) return;
    int cnt = count[node];
    int end = starts_end[node];    // == beg + cnt after place_kernel
    int beg = end - cnt;
    int rlane = lane & 31;         // lanes>=32 compute a dummy accr (never written)
    float S = 0.0f, accx = 0.0f, accr = 0.0f;
    int k = 0;
    for (; k + 4 <= cnt; k += 4) {
        int4 p0 = pack[beg + k + 0];
        int4 p1 = pack[beg + k + 1];
        int4 p2 = pack[beg + k + 2];
        int4 p3 = pack[beg + k + 3];
        float x0 = x[(size_t)p0.x * E_HID + lane];
        float x1 = x[(size_t)p1.x * E_HID + lane];
        float x2 = x[(size_t)p2.x * E_HID + lane];
        float x3 = x[(size_t)p3.x * E_HID + lane];
        float r0 = rel_emb[p0.y * R_HID + rlane];
        float r1 = rel_emb[p1.y * R_HID + rlane];
        float r2 = rel_emb[p2.y * R_HID + rlane];
        float r3 = rel_emb[p3.y * R_HID + rlane];
        float se0 = __int_as_float(p0.z), se1 = __int_as_float(p1.z);
        float se2 = __int_as_float(p2.z), se3 = __int_as_float(p3.z);
        S    += (se0 + se1) + (se2 + se3);
        accx += se0 * x0 + se1 * x1 + se2 * x2 + se3 * x3;
        accr += se0 * r0 + se1 * r1 + se2 * r2 + se3 * r3;
    }
    for (; k < cnt; k++) {
        int4 p = pack[beg + k];
        float se = __int_as_float(p.z);
        S    += se;
        accx += se * x[(size_t)p.x * E_HID + lane];
        accr += se * rel_emb[p.y * R_HID + rlane];
    }
    float wv = 1.0f / (S + EPSF);
    float xv = x[(size_t)node * E_HID + lane];
    float* o = out + (size_t)node * D_OUT;
    o[lane]      = xv;                              // cols 0:64   = x
    o[64 + lane] = fmaxf(S * wv * xv, 0.0f);        // cols 64:128 = relu(alpha*x)
    if (lane < R_HID)
        o[128 + lane] = fmaxf(accr * wv, 0.0f);     // cols 128:160 = rel part
    o[160 + lane] = fmaxf(accx * wv, 0.0f);         // cols 160:224 = x[ej] part
}

extern "C" void kernel_launch(void* const* d_in, const int* in_sizes, int n_in,
                              void* d_out, int out_size, void* d_ws, size_t ws_size,
                              hipStream_t stream) {
    const float* x        = (const float*)d_in[0];               // [N, 64]
    const int*   edge_all = (const int*)  d_in[1];               // [2, E] flat
    const int*   rel      = (const int*)  d_in[2];               // [E]
    const float* rel_emb  = (const float*)d_in[3];               // [500, 32]
    const float* ww       = (const float*)d_in[4];               // [160]
    float*       out      = (float*)d_out;                       // [N, 224]

    const int* ei = edge_all;            // destinations (group index)
    const int* ej = edge_all + N_EDGES;  // sources

    // workspace layout (pack first -> 16B alignment):
    // pack[E] (int4) | s_i[N] | s_j[N] | s_r[512] | count[N] | starts[N] | bsums[512]
    int4*  pack   = (int4*)d_ws;                       // 8 MB
    float* s_i    = (float*)(pack + N_EDGES);
    float* s_j    = s_i + N_NODES;
    float* s_r    = s_j + N_NODES;
    int*   count  = (int*)(s_r + 512);
    int*   starts = count + N_NODES;
    int*   bsums  = starts + N_NODES;

    hipMemsetAsync(count, 0, (size_t)N_NODES * sizeof(int), stream);

    fused_pre_kernel<<<PRE_GRID, 256, 0, stream>>>(x, rel_emb, ww, ei,
                                                   s_i, s_j, s_r, count);
    scan1_kernel<<<SCAN_NB, SCAN_B, 0, stream>>>(count, starts, bsums);
    scan2_kernel<<<1, 256, 0, stream>>>(bsums);
    scan3_kernel<<<SCAN_NB, SCAN_B, 0, stream>>>(starts, bsums);
    place_kernel<<<(N_EDGES + 255) / 256, 256, 0, stream>>>(ei, ej, rel,
                                                            s_i, s_j, s_r,
                                                            starts, pack);
    node_aggregate_kernel<<<(N_NODES + 3) / 4, 256, 0, stream>>>(
        pack, starts, count, x, rel_emb, out);
}